// Round 6
// baseline (531.103 us; speedup 1.0000x reference)
//
#include <hip/hip_runtime.h>

// ---------------------------------------------------------------------------
// PointNet2-AT inference pipeline, bf16 MFMA GEMMs + fp32 epilogues.
// B=16, N=4096 -> M = 65536 rows everywhere.
// R1: live-range-overlaid workspace. R2: global_load_lds 16B staging.
// R4: XCD-aware swizzle (FETCH 265->48MB). R5: BK=64 + XOR bank-deswizzle
//     (conflicts -> 0, S3 138.9->109.8us).
// R6: 256x128 block tile (wave = 64x128, af[4] x bf[8]): MFMA per staged
//     byte +33%, LDS-read per MFMA -25%, barrier-drain events per MFMA /2.
//     Logits -> 8 slices. Pool grid z=64.
// ---------------------------------------------------------------------------

#define M_ROWS 65536
#define MB ((size_t)1 << 20)

typedef __bf16 bf16x8 __attribute__((ext_vector_type(8)));
typedef float floatx4 __attribute__((ext_vector_type(4)));

__device__ __forceinline__ float b2f(ushort u) {
    unsigned int x = ((unsigned int)u) << 16;
    float f;
    __builtin_memcpy(&f, &x, 4);
    return f;
}
__device__ __forceinline__ ushort f2bf(float f) {
    unsigned int x;
    __builtin_memcpy(&x, &f, 4);
    unsigned int r = x + 0x7fffu + ((x >> 16) & 1u);  // RNE
    return (ushort)(r >> 16);
}

// async global->LDS, 16B per lane; LDS dest = wave-uniform base + lane*16
__device__ __forceinline__ void gl_lds16(const ushort* g, ushort* l) {
    __builtin_amdgcn_global_load_lds(
        (const __attribute__((address_space(1))) unsigned int*)g,
        (__attribute__((address_space(3))) unsigned int*)l, 16, 0, 0);
}

// ---------------------------------------------------------------------------
// Prep: transpose+convert weights fp32[K,N] -> bf16 Wt[N,Kp] (zero-padded K),
// and fold BN params into scale/shift arrays.
// ---------------------------------------------------------------------------
struct PrepArgs {
    const float* wsrc[5]; ushort* wdst[5]; int wK[5], wN[5], wKp[5], wcount[5];
    const float* g[5]; const float* bb[5]; const float* mm[5]; const float* vv[5];
    float* sc[5]; float* sh[5]; int C[5];
};

__global__ __launch_bounds__(256) void prep_kernel(PrepArgs p, int totalW, int totalC) {
    int idx = blockIdx.x * 256 + threadIdx.x;
    if (idx < totalW) {
        int s = 0, base = 0;
        for (s = 0; s < 5; ++s) {
            if (idx < base + p.wcount[s]) break;
            base += p.wcount[s];
        }
        int local = idx - base;
        int n = local / p.wKp[s];
        int k = local - n * p.wKp[s];
        p.wdst[s][local] = (k < p.wK[s]) ? f2bf(p.wsrc[s][k * p.wN[s] + n]) : (ushort)0;
    } else {
        int cidx = idx - totalW;
        if (cidx < totalC) {
            int s = 0, base = 0;
            for (s = 0; s < 5; ++s) {
                if (cidx < base + p.C[s]) break;
                base += p.C[s];
            }
            int c = cidx - base;
            float scv = p.g[s][c] * rsqrtf(p.vv[s][c] + 1e-5f);
            p.sc[s][c] = scv;
            p.sh[s][c] = p.bb[s][c] - p.mm[s][c] * scv;
        }
    }
}

__global__ __launch_bounds__(256) void zero_kernel(float* __restrict__ p, int n) {
    int i = blockIdx.x * 256 + threadIdx.x;
    if (i < n) p[i] = 0.0f;
}

// ---------------------------------------------------------------------------
// Layer 1: [M,6] @ [6,64] + BN + ReLU -> bf16 [M,64].  (K=6: vector kernel)
// ---------------------------------------------------------------------------
__global__ __launch_bounds__(256) void l1_kernel(
    const float* __restrict__ xyz, const float* __restrict__ pts,
    const float* __restrict__ w1, const float* __restrict__ g,
    const float* __restrict__ b, const float* __restrict__ m,
    const float* __restrict__ v, ushort* __restrict__ f1) {
    __shared__ float w[384];
    __shared__ float sc[64], sh[64];
    int tid = threadIdx.x;
    if (tid < 64) {
        float s = g[tid] * rsqrtf(v[tid] + 1e-5f);
        sc[tid] = s;
        sh[tid] = b[tid] - m[tid] * s;
    }
    for (int i = tid; i < 384; i += 256) w[i] = w1[i];
    __syncthreads();
    int r = blockIdx.x * 4 + (tid >> 6);
    int c = tid & 63;
    float x0 = xyz[r * 3], x1 = xyz[r * 3 + 1], x2 = xyz[r * 3 + 2];
    float p0 = pts[r * 3], p1 = pts[r * 3 + 1], p2 = pts[r * 3 + 2];
    float a = x0 * w[c] + x1 * w[64 + c] + x2 * w[128 + c] +
              p0 * w[192 + c] + p1 * w[256 + c] + p2 * w[320 + c];
    a = fmaxf(a * sc[c] + sh[c], 0.0f);
    f1[(size_t)r * 64 + c] = f2bf(a);
}

// ---------------------------------------------------------------------------
// GEMM: C[M,N] = ReLU(BN(A[M,K] @ W[K,N])), A bf16 [M,K], Wt bf16 [N,K].
// Block tile 256(M) x 128(N), BK=64, 256 threads / 4 waves.
// Wave wid computes rows [wid*64, +64) x all 128 cols: af[4] x bf[8],
// acc[4][8] 16x16x32 MFMA (2 K-halves per iter).
// Grid: 1D, XCD-swizzled: L = chunk*(8*numN) + nt*8 + xcd;
//   bm0 = (chunk*8+xcd)*256; bn0 = nt*128.  (M/256)%8==0.
// LDS As[256][64], Bs[128][64] with XOR 16B-block swizzle:
//   LDS[r][s] = global[r][s ^ (r&7)]; reads use slot = g ^ (lm&7) ->
//   conflict-free (verified 0 conflicts in R5).
// Fused logits (S3): wave covers the whole N-tile -> per-row partial over
//   128 cols, 16-lane reduce, store slice logitsP[nt][row]. 8 slices.
// K % 64 == 0 required.
// ---------------------------------------------------------------------------
__global__ __launch_bounds__(256) void gemm_bn_relu(
    const ushort* __restrict__ A, const ushort* __restrict__ Wt,
    const float* __restrict__ scale, const float* __restrict__ shift,
    ushort* __restrict__ C, int N, int K, int numN,
    const float* __restrict__ attw, float* __restrict__ logitsP) {
    __shared__ ushort As[256 * 64];
    __shared__ ushort Bs[128 * 64];
    const int tid = threadIdx.x;
    const int g8 = numN * 8;
    const int chunk = blockIdx.x / g8;
    const int rem = blockIdx.x - chunk * g8;
    const int nt = rem >> 3;
    const int xcd = rem & 7;
    const int bn0 = nt * 128;
    const int bm0 = (chunk * 8 + xcd) * 256;

    const int wid = tid >> 6, ln = tid & 63;
    const int lm = ln & 15, q = ln >> 4;
    const int sx = lm & 7;  // fragment-read XOR key (row&7 == lm&7)

    floatx4 acc[4][8];
#pragma unroll
    for (int i = 0; i < 4; ++i)
#pragma unroll
        for (int j = 0; j < 8; ++j) acc[i][j] = (floatx4){0.f, 0.f, 0.f, 0.f};

    // staging lane mapping: per call covers 32 rows x 8 16B-blocks
    const int srow = tid >> 3;            // 0..31
    const int sb = tid & 7;               // LDS dest 16B-block
    const int sgb = sb ^ (srow & 7);      // global source block (XOR swizzle)
    const ushort* aP[8];
    const ushort* bP[4];
#pragma unroll
    for (int l = 0; l < 8; ++l)
        aP[l] = &A[(size_t)(bm0 + l * 32 + srow) * K + (sgb << 3)];
#pragma unroll
    for (int l = 0; l < 4; ++l)
        bP[l] = &Wt[(size_t)(bn0 + l * 32 + srow) * K + (sgb << 3)];
    ushort* aL = &As[wid * 512];  // wave-uniform; + l*2048 per 32-row slab
    ushort* bL = &Bs[wid * 512];

    for (int kt = 0; kt < K; kt += 64) {
#pragma unroll
        for (int l = 0; l < 8; ++l) gl_lds16(aP[l], aL + l * 2048);
#pragma unroll
        for (int l = 0; l < 4; ++l) gl_lds16(bP[l], bL + l * 2048);
#pragma unroll
        for (int l = 0; l < 8; ++l) aP[l] += 64;
#pragma unroll
        for (int l = 0; l < 4; ++l) bP[l] += 64;
        asm volatile("s_waitcnt vmcnt(0)" ::: "memory");
        __syncthreads();
#pragma unroll
        for (int h = 0; h < 2; ++h) {
            const int slot = ((h << 2) | q) ^ sx;  // lane-constant per h
            bf16x8 af[4], bf[8];
#pragma unroll
            for (int i = 0; i < 4; ++i)
                af[i] = *(const bf16x8*)(&As[(wid * 64 + i * 16 + lm) * 64 + (slot << 3)]);
#pragma unroll
            for (int i = 0; i < 8; ++i)
                bf[i] = *(const bf16x8*)(&Bs[(i * 16 + lm) * 64 + (slot << 3)]);
#pragma unroll
            for (int mi = 0; mi < 4; ++mi)
#pragma unroll
                for (int ni = 0; ni < 8; ++ni)
                    acc[mi][ni] = __builtin_amdgcn_mfma_f32_16x16x32_bf16(
                        af[mi], bf[ni], acc[mi][ni], 0, 0, 0);
        }
        __syncthreads();
    }

    float s[8], t[8], aw[8];
#pragma unroll
    for (int ni = 0; ni < 8; ++ni) {
        int gcol = bn0 + ni * 16 + lm;
        s[ni] = scale[gcol];
        t[ni] = shift[gcol];
        aw[ni] = attw ? attw[gcol] : 0.0f;
    }
#pragma unroll
    for (int mi = 0; mi < 4; ++mi) {
        int grow0 = bm0 + wid * 64 + mi * 16 + q * 4;
#pragma unroll
        for (int r = 0; r < 4; ++r) {
            float p = 0.0f;
#pragma unroll
            for (int ni = 0; ni < 8; ++ni) {
                int gcol = bn0 + ni * 16 + lm;
                float val = fmaxf(acc[mi][ni][r] * s[ni] + t[ni], 0.0f);
                C[(size_t)(grow0 + r) * N + gcol] = f2bf(val);
                p += val * aw[ni];
            }
            if (logitsP) {
#pragma unroll
                for (int o = 8; o > 0; o >>= 1) p += __shfl_xor(p, o, 16);
                if (lm == 0)
                    logitsP[(size_t)nt * M_ROWS + grow0 + r] = p;
            }
        }
    }
}

// ---------------------------------------------------------------------------
// Gate: s = sigmoid(f3 . att_w + att_b); G = [bf16(xyz), f3*s, 0pad] [M,320]
// ---------------------------------------------------------------------------
__global__ __launch_bounds__(256) void gate_kernel(
    const ushort* __restrict__ f3, const float* __restrict__ attw,
    const float* __restrict__ attb, const float* __restrict__ xyz,
    ushort* __restrict__ G) {
    int tid = threadIdx.x;
    int ln = tid & 63, wid = tid >> 6;
    int r = blockIdx.x * 4 + wid;
    ushort4 fv = *(const ushort4*)&f3[(size_t)r * 256 + ln * 4];
    float f0 = b2f(fv.x), f1 = b2f(fv.y), f2 = b2f(fv.z), f3v = b2f(fv.w);
    float4 aw = *(const float4*)&attw[ln * 4];
    float sum = f0 * aw.x + f1 * aw.y + f2 * aw.z + f3v * aw.w;
#pragma unroll
    for (int o = 32; o > 0; o >>= 1) sum += __shfl_xor(sum, o);
    float s = 1.0f / (1.0f + expf(-(sum + attb[0])));
    size_t gb = (size_t)r * 320;
    G[gb + 3 + ln * 4 + 0] = f2bf(f0 * s);
    G[gb + 3 + ln * 4 + 1] = f2bf(f1 * s);
    G[gb + 3 + ln * 4 + 2] = f2bf(f2 * s);
    G[gb + 3 + ln * 4 + 3] = f2bf(f3v * s);
    if (ln < 3) G[gb + ln] = f2bf(xyz[r * 3 + ln]);
    if (ln >= 3) G[gb + 256 + ln] = 0;  // cols 259..319 zero pad
}

// ---------------------------------------------------------------------------
// Softmax over N=4096 per batch (logits = sum of 8 partial slices).
// ---------------------------------------------------------------------------
__global__ __launch_bounds__(1024) void softmax_kernel(
    const float* __restrict__ logitsP, float* __restrict__ alpha) {
    __shared__ float red[1024];
    int b = blockIdx.x, t = threadIdx.x;
    float4 v = (float4){0.f, 0.f, 0.f, 0.f};
#pragma unroll
    for (int j = 0; j < 8; ++j) {
        float4 pv = *(const float4*)&logitsP[(size_t)j * M_ROWS + b * 4096 + t * 4];
        v.x += pv.x; v.y += pv.y; v.z += pv.z; v.w += pv.w;
    }
    float mx = fmaxf(fmaxf(v.x, v.y), fmaxf(v.z, v.w));
    red[t] = mx;
    __syncthreads();
    for (int s = 512; s > 0; s >>= 1) {
        if (t < s) red[t] = fmaxf(red[t], red[t + s]);
        __syncthreads();
    }
    float M = red[0];
    __syncthreads();
    float e0 = expf(v.x - M), e1 = expf(v.y - M), e2 = expf(v.z - M), e3 = expf(v.w - M);
    red[t] = e0 + e1 + e2 + e3;
    __syncthreads();
    for (int s = 512; s > 0; s >>= 1) {
        if (t < s) red[t] += red[t + s];
        __syncthreads();
    }
    float inv = 1.0f / red[0];
    *(float4*)&alpha[b * 4096 + t * 4] = make_float4(e0 * inv, e1 * inv, e2 * inv, e3 * inv);
}

// ---------------------------------------------------------------------------
// Pool: pooled[b,c] = sum_n alpha[b,n]*g3[b,n,c]; each thread: 4 cols (ushort4)
// grid (1, 16 b, 64 nsplit) x 256
// ---------------------------------------------------------------------------
__global__ __launch_bounds__(256) void pool_kernel(
    const ushort* __restrict__ g3, const float* __restrict__ alpha,
    float* __restrict__ pooled) {
    int c4 = threadIdx.x * 4;
    int b = blockIdx.y;
    int n0 = blockIdx.z * 64;
    const ushort* base = g3 + ((size_t)b * 4096 + n0) * 1024 + c4;
    const float* al = alpha + b * 4096 + n0;
    float a0 = 0.f, a1 = 0.f, a2 = 0.f, a3 = 0.f;
#pragma unroll 4
    for (int n = 0; n < 64; ++n) {
        float w = al[n];
        ushort4 gv = *(const ushort4*)&base[(size_t)n * 1024];
        a0 += w * b2f(gv.x); a1 += w * b2f(gv.y);
        a2 += w * b2f(gv.z); a3 += w * b2f(gv.w);
    }
    float* pd = &pooled[b * 1024 + c4];
    atomicAdd(pd + 0, a0); atomicAdd(pd + 1, a1);
    atomicAdd(pd + 2, a2); atomicAdd(pd + 3, a3);
}

// ---------------------------------------------------------------------------
// Head
// ---------------------------------------------------------------------------
__global__ __launch_bounds__(256) void head1_kernel(
    const float* __restrict__ pooled, const float* __restrict__ w,
    const float* __restrict__ g, const float* __restrict__ bb,
    const float* __restrict__ m, const float* __restrict__ v,
    float* __restrict__ h1) {
    int idx = blockIdx.x * 256 + threadIdx.x;  // 16*512
    int b = idx >> 9, c = idx & 511;
    float sc = g[c] * rsqrtf(v[c] + 1e-5f);
    float sh = bb[c] - m[c] * sc;
    const float* pr = pooled + b * 1024;
    float acc = 0.0f;
    for (int k = 0; k < 1024; ++k) acc += pr[k] * w[k * 512 + c];
    h1[idx] = fmaxf(acc * sc + sh, 0.0f);
}

__global__ __launch_bounds__(256) void head2_kernel(
    const float* __restrict__ h1, const float* __restrict__ w,
    const float* __restrict__ g, const float* __restrict__ bb,
    const float* __restrict__ m, const float* __restrict__ v,
    float* __restrict__ h2) {
    int b = blockIdx.x, c = threadIdx.x;  // 16 x 256
    float sc = g[c] * rsqrtf(v[c] + 1e-5f);
    float sh = bb[c] - m[c] * sc;
    const float* hr = h1 + b * 512;
    float acc = 0.0f;
    for (int k = 0; k < 512; ++k) acc += hr[k] * w[k * 256 + c];
    h2[b * 256 + c] = fmaxf(acc * sc + sh, 0.0f);
}

__global__ __launch_bounds__(64) void head3_kernel(
    const float* __restrict__ h2, const float* __restrict__ pw,
    const float* __restrict__ pb, float* __restrict__ out) {
    int b = blockIdx.x, ln = threadIdx.x;
    float4 hv = *(const float4*)&h2[b * 256 + ln * 4];
    float4 wv = *(const float4*)&pw[ln * 4];
    float sum = hv.x * wv.x + hv.y * wv.y + hv.z * wv.z + hv.w * wv.w;
#pragma unroll
    for (int o = 32; o > 0; o >>= 1) sum += __shfl_xor(sum, o);
    if (ln == 0) out[b] = sum + pb[0];
}

// ---------------------------------------------------------------------------
extern "C" void kernel_launch(void* const* d_in, const int* in_sizes, int n_in,
                              void* d_out, int out_size, void* d_ws, size_t ws_size,
                              hipStream_t stream) {
    (void)in_sizes; (void)n_in; (void)out_size; (void)ws_size;
    const float* xyz = (const float*)d_in[0];
    const float* pts = (const float*)d_in[1];
    const float* sa1_w1 = (const float*)d_in[2];
    const float* bn1g = (const float*)d_in[3];
    const float* bn1b = (const float*)d_in[4];
    const float* bn1m = (const float*)d_in[5];
    const float* bn1v = (const float*)d_in[6];
    const float* sa1_w2 = (const float*)d_in[7];
    const float* bn2g = (const float*)d_in[8];
    const float* bn2b = (const float*)d_in[9];
    const float* bn2m = (const float*)d_in[10];
    const float* bn2v = (const float*)d_in[11];
    const float* sa1_w3 = (const float*)d_in[12];
    const float* bn3g = (const float*)d_in[13];
    const float* bn3b = (const float*)d_in[14];
    const float* bn3m = (const float*)d_in[15];
    const float* bn3v = (const float*)d_in[16];
    const float* att1w = (const float*)d_in[17];
    const float* att1b = (const float*)d_in[18];
    const float* sa3_w1 = (const float*)d_in[19];
    const float* s1g = (const float*)d_in[20];
    const float* s1b = (const float*)d_in[21];
    const float* s1m = (const float*)d_in[22];
    const float* s1v = (const float*)d_in[23];
    const float* sa3_w2 = (const float*)d_in[24];
    const float* s2g = (const float*)d_in[25];
    const float* s2b = (const float*)d_in[26];
    const float* s2m = (const float*)d_in[27];
    const float* s2v = (const float*)d_in[28];
    const float* sa3_w3 = (const float*)d_in[29];
    const float* s3g = (const float*)d_in[30];
    const float* s3b = (const float*)d_in[31];
    const float* s3m = (const float*)d_in[32];
    const float* s3v = (const float*)d_in[33];
    const float* att3w = (const float*)d_in[34];
    const float* fc1w = (const float*)d_in[35];
    const float* h1g = (const float*)d_in[36];
    const float* h1b = (const float*)d_in[37];
    const float* h1m = (const float*)d_in[38];
    const float* h1v = (const float*)d_in[39];
    const float* fc2w = (const float*)d_in[40];
    const float* h2g = (const float*)d_in[41];
    const float* h2b = (const float*)d_in[42];
    const float* h2m = (const float*)d_in[43];
    const float* h2v = (const float*)d_in[44];
    const float* predw = (const float*)d_in[45];
    const float* predb = (const float*)d_in[46];
    float* out = (float*)d_out;

    // ---- workspace: small linear region, then overlaid big region ----
    char* wsb = (char*)d_ws;
    size_t off = 0;
    auto alloc = [&](size_t bytes) -> void* {
        off = (off + 255) & ~(size_t)255;
        void* p = wsb + off;
        off += bytes;
        return p;
    };
    ushort* Wt2 = (ushort*)alloc(128 * 64 * 2);
    ushort* Wt3 = (ushort*)alloc(256 * 128 * 2);
    ushort* WtS1 = (ushort*)alloc(256 * 320 * 2);
    ushort* WtS2 = (ushort*)alloc(512 * 256 * 2);
    ushort* WtS3 = (ushort*)alloc(1024 * 512 * 2);
    float* sc2 = (float*)alloc(128 * 4);  float* sh2 = (float*)alloc(128 * 4);
    float* sc3 = (float*)alloc(256 * 4);  float* sh3 = (float*)alloc(256 * 4);
    float* scS1 = (float*)alloc(256 * 4); float* shS1 = (float*)alloc(256 * 4);
    float* scS2 = (float*)alloc(512 * 4); float* shS2 = (float*)alloc(512 * 4);
    float* scS3 = (float*)alloc(1024 * 4); float* shS3 = (float*)alloc(1024 * 4);
    float* logitsP = (float*)alloc((size_t)8 * M_ROWS * 4);  // 2 MB partials
    float* alpha = (float*)alloc((size_t)M_ROWS * 4);
    float* pooled = (float*)alloc(16 * 1024 * 4);
    float* h1buf = (float*)alloc(16 * 512 * 4);
    float* h2buf = (float*)alloc(16 * 256 * 4);

    // big region, overlaid by live range (G [M,320] = 40 MB).
    off = (off + MB - 1) & ~(MB - 1);
    char* bigA = wsb + off;            // 128 MB
    char* bigB = bigA + 128 * MB;      // 64 MB
    ushort* f1 = (ushort*)(bigA);             //  8 MB  [L1, G2)
    ushort* f2 = (ushort*)(bigA + 8 * MB);    // 16 MB  [G2, G3)
    ushort* f3 = (ushort*)(bigA + 24 * MB);   // 32 MB  [G3, gate)
    ushort* G  = (ushort*)(bigA + 56 * MB);   // 40 MB  [gate, S1)
    ushort* g1 = (ushort*)(bigA + 96 * MB);   // 32 MB  [S1, S2)
    ushort* g3 = (ushort*)(bigA);             // 128 MB [S3, pool)
    ushort* g2 = (ushort*)(bigB);             // 64 MB  [S2, S3)

    // ---- prep ----
    PrepArgs pa;
    const float* wsrcs[5] = {sa1_w2, sa1_w3, sa3_w1, sa3_w2, sa3_w3};
    ushort* wdsts[5] = {Wt2, Wt3, WtS1, WtS2, WtS3};
    int wKs[5] = {64, 128, 259, 256, 512};
    int wNs[5] = {128, 256, 256, 512, 1024};
    int wKps[5] = {64, 128, 320, 256, 512};
    const float* gs[5] = {bn2g, bn3g, s1g, s2g, s3g};
    const float* bbs[5] = {bn2b, bn3b, s1b, s2b, s3b};
    const float* mms[5] = {bn2m, bn3m, s1m, s2m, s3m};
    const float* vvs[5] = {bn2v, bn3v, s1v, s2v, s3v};
    float* scs[5] = {sc2, sc3, scS1, scS2, scS3};
    float* shs[5] = {sh2, sh3, shS1, shS2, shS3};
    int Cs[5] = {128, 256, 256, 512, 1024};
    int totalW = 0, totalC = 0;
    for (int i = 0; i < 5; ++i) {
        pa.wsrc[i] = wsrcs[i]; pa.wdst[i] = wdsts[i];
        pa.wK[i] = wKs[i]; pa.wN[i] = wNs[i]; pa.wKp[i] = wKps[i];
        pa.wcount[i] = wNs[i] * wKps[i];
        totalW += pa.wcount[i];
        pa.g[i] = gs[i]; pa.bb[i] = bbs[i]; pa.mm[i] = mms[i]; pa.vv[i] = vvs[i];
        pa.sc[i] = scs[i]; pa.sh[i] = shs[i]; pa.C[i] = Cs[i];
        totalC += Cs[i];
    }
    int prepBlocks = (totalW + totalC + 255) / 256;
    prep_kernel<<<prepBlocks, 256, 0, stream>>>(pa, totalW, totalC);
    zero_kernel<<<(16 * 1024 + 255) / 256, 256, 0, stream>>>(pooled, 16 * 1024);

    // ---- layer 1 ----
    l1_kernel<<<M_ROWS / 4, 256, 0, stream>>>(xyz, pts, sa1_w1, bn1g, bn1b, bn1m, bn1v, f1);
    // ---- layers 2,3 (grid = (M/256)*numN, XCD-swizzled in-kernel) ----
    gemm_bn_relu<<<256 * 1, 256, 0, stream>>>(f1, Wt2, sc2, sh2, f2, 128, 64, 1, nullptr, nullptr);
    gemm_bn_relu<<<256 * 2, 256, 0, stream>>>(f2, Wt3, sc3, sh3, f3, 256, 128, 2, nullptr, nullptr);
    // ---- gate + concat (G stride 320, K-padded) ----
    gate_kernel<<<M_ROWS / 4, 256, 0, stream>>>(f3, att1w, att1b, xyz, G);
    // ---- SA3 ----
    gemm_bn_relu<<<256 * 2, 256, 0, stream>>>(G, WtS1, scS1, shS1, g1, 256, 320, 2, nullptr, nullptr);
    gemm_bn_relu<<<256 * 4, 256, 0, stream>>>(g1, WtS2, scS2, shS2, g2, 512, 256, 4, nullptr, nullptr);
    // S3: fused attention-logits partial slices (8, no atomics)
    gemm_bn_relu<<<256 * 8, 256, 0, stream>>>(g2, WtS3, scS3, shS3, g3, 1024, 512, 8, att3w, logitsP);
    // ---- attention pooling ----
    softmax_kernel<<<16, 1024, 0, stream>>>(logitsP, alpha);
    pool_kernel<<<dim3(1, 16, 64), 256, 0, stream>>>(g3, alpha, pooled);
    // ---- head ----
    head1_kernel<<<32, 256, 0, stream>>>(pooled, fc1w, h1g, h1b, h1m, h1v, h1buf);
    head2_kernel<<<16, 256, 0, stream>>>(h1buf, fc2w, h2g, h2b, h2m, h2v, h2buf);
    head3_kernel<<<16, 64, 0, stream>>>(h2buf, predw, predb, out);
}

// Round 7
// 381.554 us; speedup vs baseline: 1.3919x; 1.3919x over previous
//
#include <hip/hip_runtime.h>

// ---------------------------------------------------------------------------
// PointNet2-AT inference pipeline, bf16 MFMA GEMMs + fp32 epilogues.
// B=16, N=4096 -> M = 65536 rows everywhere.
// R5 GEMM config (proven): 128x128 tile, BK=64, XOR bank-deswizzle,
//   global_load_lds 16B, XCD-aware grid swizzle. (R6's 256x128 tile cut
//   occupancy to 1 wave/SIMD via 288 unified regs -> reverted.)
// R7: tail attack. Tiled-transpose prep (coalesced, folds BN + pooled zero),
//   G re-layout [f*s | xyz | pad] with row-permuted WtS1 so G3 writes
//   in-place into G (ldc=320, f3 buffer deleted), aligned gate stores,
//   wave-per-output heads with transposed fp32 weights.
// ---------------------------------------------------------------------------

#define M_ROWS 65536
#define MB ((size_t)1 << 20)

typedef __bf16 bf16x8 __attribute__((ext_vector_type(8)));
typedef float floatx4 __attribute__((ext_vector_type(4)));

__device__ __forceinline__ float b2f(ushort u) {
    unsigned int x = ((unsigned int)u) << 16;
    float f;
    __builtin_memcpy(&f, &x, 4);
    return f;
}
__device__ __forceinline__ ushort f2bf(float f) {
    unsigned int x;
    __builtin_memcpy(&x, &f, 4);
    unsigned int r = x + 0x7fffu + ((x >> 16) & 1u);  // RNE
    return (ushort)(r >> 16);
}

// async global->LDS, 16B per lane; LDS dest = wave-uniform base + lane*16
__device__ __forceinline__ void gl_lds16(const ushort* g, ushort* l) {
    __builtin_amdgcn_global_load_lds(
        (const __attribute__((address_space(1))) unsigned int*)g,
        (__attribute__((address_space(3))) unsigned int*)l, 16, 0, 0);
}

// ---------------------------------------------------------------------------
// Prep2: LDS-tiled transpose (coalesced both sides) of 5 bf16 GEMM weights
// (w==2 = sa3_w1 with row permutation for the [f|xyz|pad] G layout) and
// 2 fp32 head weights; y==7 slice folds BN consts and zeroes pooled.
// ---------------------------------------------------------------------------
struct Prep2Args {
    const float* src[7]; void* dst[7];
    int K[7], N[7], Kp[7], tiles[7], isBF[7];
    const float* g[5]; const float* bb[5]; const float* mm[5]; const float* vv[5];
    float* sc[5]; float* sh[5]; int C[5];
    float* pooled;
};

__global__ __launch_bounds__(256) void prep2_kernel(Prep2Args p) {
    int w = blockIdx.y;
    if (w < 7) {
        if ((int)blockIdx.x >= p.tiles[w]) return;
        int ntn = p.N[w] >> 5;
        int tk = blockIdx.x / ntn, tn = blockIdx.x - tk * ntn;
        int k0 = tk << 5, n0 = tn << 5;
        __shared__ float tile[32][33];
        int tx = threadIdx.x & 31, ty0 = threadIdx.x >> 5;
        const float* src = p.src[w];
        int N = p.N[w], K = p.K[w], Kp = p.Kp[w];
#pragma unroll
        for (int i = 0; i < 4; ++i) {
            int ty = ty0 + i * 8;
            int k = k0 + ty, n = n0 + tx;
            float v = 0.f;
            if (w == 2) {
                // G layout: rows 0..255 = f (orig 3..258), 256..258 = xyz
                // (orig 0..2), 259..319 = zero pad
                int kk = (k < 256) ? k + 3 : (k < 259 ? k - 256 : -1);
                if (kk >= 0) v = src[kk * N + n];
            } else if (k < K) {
                v = src[k * N + n];
            }
            tile[ty][tx] = v;
        }
        __syncthreads();
#pragma unroll
        for (int i = 0; i < 4; ++i) {
            int ty = ty0 + i * 8;
            int n = n0 + ty, k = k0 + tx;
            if (p.isBF[w])
                ((ushort*)p.dst[w])[(size_t)n * Kp + k] = f2bf(tile[tx][ty]);
            else
                ((float*)p.dst[w])[(size_t)n * Kp + k] = tile[tx][ty];
        }
    } else {
        int idx = blockIdx.x * 256 + threadIdx.x;
        if (idx < 2176) {
            int s = 0, base = 0;
            for (s = 0; s < 5; ++s) {
                if (idx < base + p.C[s]) break;
                base += p.C[s];
            }
            int c = idx - base;
            float scv = p.g[s][c] * rsqrtf(p.vv[s][c] + 1e-5f);
            p.sc[s][c] = scv;
            p.sh[s][c] = p.bb[s][c] - p.mm[s][c] * scv;
        } else {
            int z = idx - 2176;
            if (z < 16384) p.pooled[z] = 0.f;
        }
    }
}

// ---------------------------------------------------------------------------
// Layer 1: [M,6] @ [6,64] + BN + ReLU -> bf16 [M,64].  (K=6: vector kernel)
// ---------------------------------------------------------------------------
__global__ __launch_bounds__(256) void l1_kernel(
    const float* __restrict__ xyz, const float* __restrict__ pts,
    const float* __restrict__ w1, const float* __restrict__ g,
    const float* __restrict__ b, const float* __restrict__ m,
    const float* __restrict__ v, ushort* __restrict__ f1) {
    __shared__ float w[384];
    __shared__ float sc[64], sh[64];
    int tid = threadIdx.x;
    if (tid < 64) {
        float s = g[tid] * rsqrtf(v[tid] + 1e-5f);
        sc[tid] = s;
        sh[tid] = b[tid] - m[tid] * s;
    }
    for (int i = tid; i < 384; i += 256) w[i] = w1[i];
    __syncthreads();
    int r = blockIdx.x * 4 + (tid >> 6);
    int c = tid & 63;
    float x0 = xyz[r * 3], x1 = xyz[r * 3 + 1], x2 = xyz[r * 3 + 2];
    float p0 = pts[r * 3], p1 = pts[r * 3 + 1], p2 = pts[r * 3 + 2];
    float a = x0 * w[c] + x1 * w[64 + c] + x2 * w[128 + c] +
              p0 * w[192 + c] + p1 * w[256 + c] + p2 * w[320 + c];
    a = fmaxf(a * sc[c] + sh[c], 0.0f);
    f1[(size_t)r * 64 + c] = f2bf(a);
}

// ---------------------------------------------------------------------------
// GEMM (R5 config): C[M,N] = ReLU(BN(A[M,K] @ W[K,N])), A bf16 [M,K],
// Wt bf16 [N,K]. 128x128 tile, BK=64, 4 waves x (4x4) 16x16x32 MFMA.
// Grid XCD-swizzled: L = chunk*(8*numN) + nt*8 + xcd; bm0=(chunk*8+xcd)*128.
// LDS [128][64] with XOR 16B-block swizzle (0 bank conflicts, R5-verified).
// C written with leading dim ldc (for in-place G). Fused logits (S3):
// per-(nt,wc) partial over 64 cols -> slice nt*2+wc (16 slices, no atomics).
// ---------------------------------------------------------------------------
__global__ __launch_bounds__(256) void gemm_bn_relu(
    const ushort* __restrict__ A, const ushort* __restrict__ Wt,
    const float* __restrict__ scale, const float* __restrict__ shift,
    ushort* __restrict__ C, int N, int K, int numN, int ldc,
    const float* __restrict__ attw, float* __restrict__ logitsP) {
    __shared__ ushort As[128 * 64];
    __shared__ ushort Bs[128 * 64];
    const int tid = threadIdx.x;
    const int g8 = numN * 8;
    const int chunk = blockIdx.x / g8;
    const int rem = blockIdx.x - chunk * g8;
    const int nt = rem >> 3;
    const int xcd = rem & 7;
    const int bn0 = nt * 128;
    const int bm0 = (chunk * 8 + xcd) * 128;

    const int wid = tid >> 6, ln = tid & 63;
    const int wr = wid >> 1, wc = wid & 1;
    const int lm = ln & 15, q = ln >> 4;
    const int sx = lm & 7;  // fragment-read XOR key

    floatx4 acc[4][4];
#pragma unroll
    for (int i = 0; i < 4; ++i)
#pragma unroll
        for (int j = 0; j < 4; ++j) acc[i][j] = (floatx4){0.f, 0.f, 0.f, 0.f};

    const int srow = tid >> 3;            // 0..31
    const int sb = tid & 7;               // LDS dest 16B-block
    const int sgb = sb ^ (srow & 7);      // global source block (XOR swizzle)
    const ushort* aP[4];
    const ushort* bP[4];
#pragma unroll
    for (int l = 0; l < 4; ++l) {
        int row = l * 32 + srow;
        aP[l] = &A[(size_t)(bm0 + row) * K + (sgb << 3)];
        bP[l] = &Wt[(size_t)(bn0 + row) * K + (sgb << 3)];
    }
    ushort* aL = &As[wid * 512];
    ushort* bL = &Bs[wid * 512];

    for (int kt = 0; kt < K; kt += 64) {
#pragma unroll
        for (int l = 0; l < 4; ++l) gl_lds16(aP[l], aL + l * 2048);
#pragma unroll
        for (int l = 0; l < 4; ++l) gl_lds16(bP[l], bL + l * 2048);
#pragma unroll
        for (int l = 0; l < 4; ++l) { aP[l] += 64; bP[l] += 64; }
        asm volatile("s_waitcnt vmcnt(0)" ::: "memory");
        __syncthreads();
#pragma unroll
        for (int h = 0; h < 2; ++h) {
            const int slot = ((h << 2) | q) ^ sx;
            bf16x8 af[4], bf[4];
#pragma unroll
            for (int i = 0; i < 4; ++i)
                af[i] = *(const bf16x8*)(&As[(wr * 64 + i * 16 + lm) * 64 + (slot << 3)]);
#pragma unroll
            for (int i = 0; i < 4; ++i)
                bf[i] = *(const bf16x8*)(&Bs[(wc * 64 + i * 16 + lm) * 64 + (slot << 3)]);
#pragma unroll
            for (int mi = 0; mi < 4; ++mi)
#pragma unroll
                for (int ni = 0; ni < 4; ++ni)
                    acc[mi][ni] = __builtin_amdgcn_mfma_f32_16x16x32_bf16(
                        af[mi], bf[ni], acc[mi][ni], 0, 0, 0);
        }
        __syncthreads();
    }

    float s[4], t[4], aw[4];
#pragma unroll
    for (int ni = 0; ni < 4; ++ni) {
        int gcol = bn0 + wc * 64 + ni * 16 + lm;
        s[ni] = scale[gcol];
        t[ni] = shift[gcol];
        aw[ni] = attw ? attw[gcol] : 0.0f;
    }
#pragma unroll
    for (int mi = 0; mi < 4; ++mi) {
        int grow0 = bm0 + wr * 64 + mi * 16 + q * 4;
#pragma unroll
        for (int r = 0; r < 4; ++r) {
            float p = 0.0f;
#pragma unroll
            for (int ni = 0; ni < 4; ++ni) {
                int gcol = bn0 + wc * 64 + ni * 16 + lm;
                float val = fmaxf(acc[mi][ni][r] * s[ni] + t[ni], 0.0f);
                C[(size_t)(grow0 + r) * ldc + gcol] = f2bf(val);
                p += val * aw[ni];
            }
            if (logitsP) {
#pragma unroll
                for (int o = 8; o > 0; o >>= 1) p += __shfl_xor(p, o, 16);
                if (lm == 0)
                    logitsP[(size_t)(nt * 2 + wc) * M_ROWS + grow0 + r] = p;
            }
        }
    }
}

// ---------------------------------------------------------------------------
// Gate (in-place on G): row r of G holds f (cols 0..255, written by G3).
// s = sigmoid(f . att_w + b); scale f in place; append xyz (256..258),
// zero pad (259..319). Aligned ushort4 loads/stores.
// ---------------------------------------------------------------------------
__global__ __launch_bounds__(256) void gate_kernel(
    const float* __restrict__ attw, const float* __restrict__ attb,
    const float* __restrict__ xyz, ushort* __restrict__ G) {
    int tid = threadIdx.x;
    int ln = tid & 63, wv = tid >> 6;
    int r = blockIdx.x * 4 + wv;
    size_t gb = (size_t)r * 320;
    ushort4 fv = *(const ushort4*)&G[gb + ln * 4];
    float f0 = b2f(fv.x), f1 = b2f(fv.y), f2 = b2f(fv.z), f3 = b2f(fv.w);
    float4 aw = *(const float4*)&attw[ln * 4];
    float sum = f0 * aw.x + f1 * aw.y + f2 * aw.z + f3 * aw.w;
#pragma unroll
    for (int o = 32; o > 0; o >>= 1) sum += __shfl_xor(sum, o);
    float s = 1.0f / (1.0f + expf(-(sum + attb[0])));
    ushort4 ov;
    ov.x = f2bf(f0 * s); ov.y = f2bf(f1 * s);
    ov.z = f2bf(f2 * s); ov.w = f2bf(f3 * s);
    *(ushort4*)&G[gb + ln * 4] = ov;
    if (ln < 3) G[gb + 256 + ln] = f2bf(xyz[r * 3 + ln]);
    else G[gb + 256 + ln] = 0;  // cols 259..319 zero
}

// ---------------------------------------------------------------------------
// Softmax over N=4096 per batch (logits = sum of 16 partial slices).
// ---------------------------------------------------------------------------
__global__ __launch_bounds__(1024) void softmax_kernel(
    const float* __restrict__ logitsP, float* __restrict__ alpha) {
    __shared__ float red[1024];
    int b = blockIdx.x, t = threadIdx.x;
    float4 v = (float4){0.f, 0.f, 0.f, 0.f};
#pragma unroll
    for (int j = 0; j < 16; ++j) {
        float4 pv = *(const float4*)&logitsP[(size_t)j * M_ROWS + b * 4096 + t * 4];
        v.x += pv.x; v.y += pv.y; v.z += pv.z; v.w += pv.w;
    }
    float mx = fmaxf(fmaxf(v.x, v.y), fmaxf(v.z, v.w));
    red[t] = mx;
    __syncthreads();
    for (int s = 512; s > 0; s >>= 1) {
        if (t < s) red[t] = fmaxf(red[t], red[t + s]);
        __syncthreads();
    }
    float M = red[0];
    __syncthreads();
    float e0 = expf(v.x - M), e1 = expf(v.y - M), e2 = expf(v.z - M), e3 = expf(v.w - M);
    red[t] = e0 + e1 + e2 + e3;
    __syncthreads();
    for (int s = 512; s > 0; s >>= 1) {
        if (t < s) red[t] += red[t + s];
        __syncthreads();
    }
    float inv = 1.0f / red[0];
    *(float4*)&alpha[b * 4096 + t * 4] = make_float4(e0 * inv, e1 * inv, e2 * inv, e3 * inv);
}

// ---------------------------------------------------------------------------
// Pool: pooled[b,c] = sum_n alpha[b,n]*g3[b,n,c]; thread: 4 cols (ushort4)
// grid (1, 16 b, 32 nsplit) x 256
// ---------------------------------------------------------------------------
__global__ __launch_bounds__(256) void pool_kernel(
    const ushort* __restrict__ g3, const float* __restrict__ alpha,
    float* __restrict__ pooled) {
    int c4 = threadIdx.x * 4;
    int b = blockIdx.y;
    int n0 = blockIdx.z * 128;
    const ushort* base = g3 + ((size_t)b * 4096 + n0) * 1024 + c4;
    const float* al = alpha + b * 4096 + n0;
    float a0 = 0.f, a1 = 0.f, a2 = 0.f, a3 = 0.f;
#pragma unroll 4
    for (int n = 0; n < 128; ++n) {
        float w = al[n];
        ushort4 gv = *(const ushort4*)&base[(size_t)n * 1024];
        a0 += w * b2f(gv.x); a1 += w * b2f(gv.y);
        a2 += w * b2f(gv.z); a3 += w * b2f(gv.w);
    }
    float* pd = &pooled[b * 1024 + c4];
    atomicAdd(pd + 0, a0); atomicAdd(pd + 1, a1);
    atomicAdd(pd + 2, a2); atomicAdd(pd + 3, a3);
}

// ---------------------------------------------------------------------------
// Heads: wave-per-output, transposed fp32 weights (contiguous float4 reads)
// ---------------------------------------------------------------------------
__global__ __launch_bounds__(256) void head1_kernel(
    const float* __restrict__ pooled, const float* __restrict__ wt1,
    const float* __restrict__ g, const float* __restrict__ bb,
    const float* __restrict__ m, const float* __restrict__ v,
    float* __restrict__ h1) {
    int wv = (blockIdx.x * 256 + threadIdx.x) >> 6;  // 0..8191
    int ln = threadIdx.x & 63;
    int b = wv >> 9, c = wv & 511;
    const float4* wp = (const float4*)&wt1[(size_t)c * 1024];
    const float4* pp = (const float4*)&pooled[b * 1024];
    float s = 0.f;
#pragma unroll
    for (int j = 0; j < 4; ++j) {
        float4 w4 = wp[ln * 4 + j], p4 = pp[ln * 4 + j];
        s += w4.x * p4.x + w4.y * p4.y + w4.z * p4.z + w4.w * p4.w;
    }
#pragma unroll
    for (int o = 32; o > 0; o >>= 1) s += __shfl_xor(s, o);
    if (ln == 0) {
        float sc = g[c] * rsqrtf(v[c] + 1e-5f);
        float sh = bb[c] - m[c] * sc;
        h1[b * 512 + c] = fmaxf(s * sc + sh, 0.0f);
    }
}

__global__ __launch_bounds__(256) void head2_kernel(
    const float* __restrict__ h1, const float* __restrict__ wt2,
    const float* __restrict__ g, const float* __restrict__ bb,
    const float* __restrict__ m, const float* __restrict__ v,
    float* __restrict__ h2) {
    int wv = (blockIdx.x * 256 + threadIdx.x) >> 6;  // 0..4095
    int ln = threadIdx.x & 63;
    int b = wv >> 8, c = wv & 255;
    const float4* wp = (const float4*)&wt2[(size_t)c * 512];
    const float4* pp = (const float4*)&h1[b * 512];
    float s = 0.f;
#pragma unroll
    for (int j = 0; j < 2; ++j) {
        float4 w4 = wp[ln * 2 + j], p4 = pp[ln * 2 + j];
        s += w4.x * p4.x + w4.y * p4.y + w4.z * p4.z + w4.w * p4.w;
    }
#pragma unroll
    for (int o = 32; o > 0; o >>= 1) s += __shfl_xor(s, o);
    if (ln == 0) {
        float sc = g[c] * rsqrtf(v[c] + 1e-5f);
        float sh = bb[c] - m[c] * sc;
        h2[b * 256 + c] = fmaxf(s * sc + sh, 0.0f);
    }
}

__global__ __launch_bounds__(64) void head3_kernel(
    const float* __restrict__ h2, const float* __restrict__ pw,
    const float* __restrict__ pb, float* __restrict__ out) {
    int b = blockIdx.x, ln = threadIdx.x;
    float4 hv = *(const float4*)&h2[b * 256 + ln * 4];
    float4 wv = *(const float4*)&pw[ln * 4];
    float sum = hv.x * wv.x + hv.y * wv.y + hv.z * wv.z + hv.w * wv.w;
#pragma unroll
    for (int o = 32; o > 0; o >>= 1) sum += __shfl_xor(sum, o);
    if (ln == 0) out[b] = sum + pb[0];
}

// ---------------------------------------------------------------------------
extern "C" void kernel_launch(void* const* d_in, const int* in_sizes, int n_in,
                              void* d_out, int out_size, void* d_ws, size_t ws_size,
                              hipStream_t stream) {
    (void)in_sizes; (void)n_in; (void)out_size; (void)ws_size;
    const float* xyz = (const float*)d_in[0];
    const float* pts = (const float*)d_in[1];
    const float* sa1_w1 = (const float*)d_in[2];
    const float* bn1g = (const float*)d_in[3];
    const float* bn1b = (const float*)d_in[4];
    const float* bn1m = (const float*)d_in[5];
    const float* bn1v = (const float*)d_in[6];
    const float* sa1_w2 = (const float*)d_in[7];
    const float* bn2g = (const float*)d_in[8];
    const float* bn2b = (const float*)d_in[9];
    const float* bn2m = (const float*)d_in[10];
    const float* bn2v = (const float*)d_in[11];
    const float* sa1_w3 = (const float*)d_in[12];
    const float* bn3g = (const float*)d_in[13];
    const float* bn3b = (const float*)d_in[14];
    const float* bn3m = (const float*)d_in[15];
    const float* bn3v = (const float*)d_in[16];
    const float* att1w = (const float*)d_in[17];
    const float* att1b = (const float*)d_in[18];
    const float* sa3_w1 = (const float*)d_in[19];
    const float* s1g = (const float*)d_in[20];
    const float* s1b = (const float*)d_in[21];
    const float* s1m = (const float*)d_in[22];
    const float* s1v = (const float*)d_in[23];
    const float* sa3_w2 = (const float*)d_in[24];
    const float* s2g = (const float*)d_in[25];
    const float* s2b = (const float*)d_in[26];
    const float* s2m = (const float*)d_in[27];
    const float* s2v = (const float*)d_in[28];
    const float* sa3_w3 = (const float*)d_in[29];
    const float* s3g = (const float*)d_in[30];
    const float* s3b = (const float*)d_in[31];
    const float* s3m = (const float*)d_in[32];
    const float* s3v = (const float*)d_in[33];
    const float* att3w = (const float*)d_in[34];
    const float* fc1w = (const float*)d_in[35];
    const float* h1g = (const float*)d_in[36];
    const float* h1b = (const float*)d_in[37];
    const float* h1m = (const float*)d_in[38];
    const float* h1v = (const float*)d_in[39];
    const float* fc2w = (const float*)d_in[40];
    const float* h2g = (const float*)d_in[41];
    const float* h2b = (const float*)d_in[42];
    const float* h2m = (const float*)d_in[43];
    const float* h2v = (const float*)d_in[44];
    const float* predw = (const float*)d_in[45];
    const float* predb = (const float*)d_in[46];
    float* out = (float*)d_out;

    // ---- workspace ----
    char* wsb = (char*)d_ws;
    size_t off = 0;
    auto alloc = [&](size_t bytes) -> void* {
        off = (off + 255) & ~(size_t)255;
        void* p = wsb + off;
        off += bytes;
        return p;
    };
    ushort* Wt2 = (ushort*)alloc(128 * 64 * 2);
    ushort* Wt3 = (ushort*)alloc(256 * 128 * 2);
    ushort* WtS1 = (ushort*)alloc(256 * 320 * 2);
    ushort* WtS2 = (ushort*)alloc(512 * 256 * 2);
    ushort* WtS3 = (ushort*)alloc(1024 * 512 * 2);
    float* wt1 = (float*)alloc(512 * 1024 * 4);  // fc1w^T
    float* wt2 = (float*)alloc(256 * 512 * 4);   // fc2w^T
    float* sc2 = (float*)alloc(128 * 4);  float* sh2 = (float*)alloc(128 * 4);
    float* sc3 = (float*)alloc(256 * 4);  float* sh3 = (float*)alloc(256 * 4);
    float* scS1 = (float*)alloc(256 * 4); float* shS1 = (float*)alloc(256 * 4);
    float* scS2 = (float*)alloc(512 * 4); float* shS2 = (float*)alloc(512 * 4);
    float* scS3 = (float*)alloc(1024 * 4); float* shS3 = (float*)alloc(1024 * 4);
    float* logitsP = (float*)alloc((size_t)16 * M_ROWS * 4);  // 4 MB
    float* alpha = (float*)alloc((size_t)M_ROWS * 4);
    float* pooled = (float*)alloc(16 * 1024 * 4);
    float* h1buf = (float*)alloc(16 * 512 * 4);
    float* h2buf = (float*)alloc(16 * 256 * 4);

    // big region, overlaid by live range (no f3 buffer: G3 writes into G).
    off = (off + MB - 1) & ~(MB - 1);
    char* bigA = wsb + off;            // 128 MB
    char* bigB = bigA + 128 * MB;      // 64 MB
    ushort* f1 = (ushort*)(bigA);             //  8 MB  [L1, G2)
    ushort* f2 = (ushort*)(bigA + 8 * MB);    // 16 MB  [G2, G3)
    ushort* G  = (ushort*)(bigA + 24 * MB);   // 40 MB  [G3, S1)  (G3 in-place)
    ushort* g1 = (ushort*)(bigA + 64 * MB);   // 32 MB  [S1, S2)
    ushort* g3 = (ushort*)(bigA);             // 128 MB [S3, pool)
    ushort* g2 = (ushort*)(bigB);             // 64 MB  [S2, S3)

    // ---- prep2 ----
    Prep2Args pa;
    const float* srcs[7] = {sa1_w2, sa1_w3, sa3_w1, sa3_w2, sa3_w3, fc1w, fc2w};
    void* dsts[7] = {Wt2, Wt3, WtS1, WtS2, WtS3, wt1, wt2};
    int Ks[7] = {64, 128, 320, 256, 512, 1024, 512};
    int Ns[7] = {128, 256, 256, 512, 1024, 512, 256};
    int Kps[7] = {64, 128, 320, 256, 512, 1024, 512};
    int isBF[7] = {1, 1, 1, 1, 1, 0, 0};
    int maxTiles = 0;
    for (int i = 0; i < 7; ++i) {
        pa.src[i] = srcs[i]; pa.dst[i] = dsts[i];
        pa.K[i] = Ks[i]; pa.N[i] = Ns[i]; pa.Kp[i] = Kps[i];
        pa.isBF[i] = isBF[i];
        pa.tiles[i] = (Kps[i] >> 5) * (Ns[i] >> 5);
        if (pa.tiles[i] > maxTiles) maxTiles = pa.tiles[i];
    }
    const float* gs[5] = {bn2g, bn3g, s1g, s2g, s3g};
    const float* bbs[5] = {bn2b, bn3b, s1b, s2b, s3b};
    const float* mms[5] = {bn2m, bn3m, s1m, s2m, s3m};
    const float* vvs[5] = {bn2v, bn3v, s1v, s2v, s3v};
    float* scs[5] = {sc2, sc3, scS1, scS2, scS3};
    float* shs[5] = {sh2, sh3, shS1, shS2, shS3};
    int Cs[5] = {128, 256, 256, 512, 1024};
    for (int i = 0; i < 5; ++i) {
        pa.g[i] = gs[i]; pa.bb[i] = bbs[i]; pa.mm[i] = mms[i]; pa.vv[i] = vvs[i];
        pa.sc[i] = scs[i]; pa.sh[i] = shs[i]; pa.C[i] = Cs[i];
    }
    pa.pooled = pooled;
    int gx = maxTiles;  // 512; also covers y==7's 73 blocks
    prep2_kernel<<<dim3(gx, 8), 256, 0, stream>>>(pa);

    // ---- layer 1 ----
    l1_kernel<<<M_ROWS / 4, 256, 0, stream>>>(xyz, pts, sa1_w1, bn1g, bn1b, bn1m, bn1v, f1);
    // ---- layers 2,3 ----
    gemm_bn_relu<<<512 * 1, 256, 0, stream>>>(f1, Wt2, sc2, sh2, f2, 128, 64, 1, 128, nullptr, nullptr);
    // G3 writes in place into G (cols 0..255 of 320-stride rows)
    gemm_bn_relu<<<512 * 2, 256, 0, stream>>>(f2, Wt3, sc3, sh3, G, 256, 128, 2, 320, nullptr, nullptr);
    // ---- gate (in place) + xyz append + pad ----
    gate_kernel<<<M_ROWS / 4, 256, 0, stream>>>(att1w, att1b, xyz, G);
    // ---- SA3 ----
    gemm_bn_relu<<<512 * 2, 256, 0, stream>>>(G, WtS1, scS1, shS1, g1, 256, 320, 2, 256, nullptr, nullptr);
    gemm_bn_relu<<<512 * 4, 256, 0, stream>>>(g1, WtS2, scS2, shS2, g2, 512, 256, 4, 512, nullptr, nullptr);
    gemm_bn_relu<<<512 * 8, 256, 0, stream>>>(g2, WtS3, scS3, shS3, g3, 1024, 512, 8, 1024, att3w, logitsP);
    // ---- attention pooling ----
    softmax_kernel<<<16, 1024, 0, stream>>>(logitsP, alpha);
    pool_kernel<<<dim3(1, 16, 32), 256, 0, stream>>>(g3, alpha, pooled);
    // ---- head ----
    head1_kernel<<<2048, 256, 0, stream>>>(pooled, wt1, h1g, h1b, h1m, h1v, h1buf);
    head2_kernel<<<1024, 256, 0, stream>>>(h1buf, wt2, h2g, h2b, h2m, h2v, h2buf);
    head3_kernel<<<16, 64, 0, stream>>>(h2buf, predw, predb, out);
}

// Round 8
// 369.505 us; speedup vs baseline: 1.4373x; 1.0326x over previous
//
#include <hip/hip_runtime.h>

// ---------------------------------------------------------------------------
// PointNet2-AT inference pipeline, bf16 MFMA GEMMs + fp32 epilogues.
// B=16, N=4096 -> M = 65536 rows everywhere.
// R5 GEMM config (proven): 128x128 tile, BK=64, XOR bank-deswizzle,
//   global_load_lds 16B, XCD-aware grid swizzle, 0 bank conflicts.
// R7: coalesced transpose prep, in-place G, wave-per-output heads. 381.6us.
// R8: SA1 megafusion — one 512-thread kernel does l1 (K=6, VALU) -> f2
//   (MFMA K=64) -> f3 (MFMA K=128, W3 streamed) -> gate (cross-wave LDS
//   reduce + sigmoid) -> scaled write to G. Deletes l1/G2/G3/gate kernels
//   and the f1/f2 buffers (~80MB round-trip traffic). G pad cols never
//   written (WtS1 pad rows are zero; 0xAA poison is a finite bf16).
// ---------------------------------------------------------------------------

#define M_ROWS 65536
#define MB ((size_t)1 << 20)

typedef __bf16 bf16x8 __attribute__((ext_vector_type(8)));
typedef float floatx4 __attribute__((ext_vector_type(4)));

__device__ __forceinline__ float b2f(ushort u) {
    unsigned int x = ((unsigned int)u) << 16;
    float f;
    __builtin_memcpy(&f, &x, 4);
    return f;
}
__device__ __forceinline__ ushort f2bf(float f) {
    unsigned int x;
    __builtin_memcpy(&x, &f, 4);
    unsigned int r = x + 0x7fffu + ((x >> 16) & 1u);  // RNE
    return (ushort)(r >> 16);
}

// async global->LDS, 16B per lane; LDS dest = wave-uniform base + lane*16
__device__ __forceinline__ void gl_lds16(const ushort* g, ushort* l) {
    __builtin_amdgcn_global_load_lds(
        (const __attribute__((address_space(1))) unsigned int*)g,
        (__attribute__((address_space(3))) unsigned int*)l, 16, 0, 0);
}

// ---------------------------------------------------------------------------
// Prep2: LDS-tiled transpose (coalesced both sides) of 5 bf16 GEMM weights
// (w==2 = sa3_w1 with row permutation for the [f|xyz|pad] G layout) and
// 2 fp32 head weights; y==7 slice folds 6 BN const sets and zeroes pooled.
// ---------------------------------------------------------------------------
struct Prep2Args {
    const float* src[7]; void* dst[7];
    int K[7], N[7], Kp[7], tiles[7], isBF[7];
    const float* g[6]; const float* bb[6]; const float* mm[6]; const float* vv[6];
    float* sc[6]; float* sh[6]; int C[6];
    float* pooled;
};

__global__ __launch_bounds__(256) void prep2_kernel(Prep2Args p) {
    int w = blockIdx.y;
    if (w < 7) {
        if ((int)blockIdx.x >= p.tiles[w]) return;
        int ntn = p.N[w] >> 5;
        int tk = blockIdx.x / ntn, tn = blockIdx.x - tk * ntn;
        int k0 = tk << 5, n0 = tn << 5;
        __shared__ float tile[32][33];
        int tx = threadIdx.x & 31, ty0 = threadIdx.x >> 5;
        const float* src = p.src[w];
        int N = p.N[w], K = p.K[w], Kp = p.Kp[w];
#pragma unroll
        for (int i = 0; i < 4; ++i) {
            int ty = ty0 + i * 8;
            int k = k0 + ty, n = n0 + tx;
            float v = 0.f;
            if (w == 2) {
                int kk = (k < 256) ? k + 3 : (k < 259 ? k - 256 : -1);
                if (kk >= 0) v = src[kk * N + n];
            } else if (k < K) {
                v = src[k * N + n];
            }
            tile[ty][tx] = v;
        }
        __syncthreads();
#pragma unroll
        for (int i = 0; i < 4; ++i) {
            int ty = ty0 + i * 8;
            int n = n0 + ty, k = k0 + tx;
            if (p.isBF[w])
                ((ushort*)p.dst[w])[(size_t)n * Kp + k] = f2bf(tile[tx][ty]);
            else
                ((float*)p.dst[w])[(size_t)n * Kp + k] = tile[tx][ty];
        }
    } else {
        int idx = blockIdx.x * 256 + threadIdx.x;
        if (idx < 2240) {
            int s = 0, base = 0;
            for (s = 0; s < 6; ++s) {
                if (idx < base + p.C[s]) break;
                base += p.C[s];
            }
            int c = idx - base;
            float scv = p.g[s][c] * rsqrtf(p.vv[s][c] + 1e-5f);
            p.sc[s][c] = scv;
            p.sh[s][c] = p.bb[s][c] - p.mm[s][c] * scv;
        } else {
            int z = idx - 2240;
            if (z < 16384) p.pooled[z] = 0.f;
        }
    }
}

// ---------------------------------------------------------------------------
// SA1 fused: per block of 128 rows (512 threads / 8 waves):
//   f1 = relu(bn1([xyz|pts] @ w1))                (K=6, VALU -> LDS F1)
//   f2 = relu(bn2(f1 @ W2))                       (MFMA K=64 -> LDS F2)
//   f3 = relu(bn3(f2 @ W3))                       (MFMA K=128, W3 streamed)
//   s  = sigmoid(f3 . att1w + att1b) per row       (cross-wave LDS reduce)
//   G[row, 0..255] = bf16(f3*s); G[row, 256..258] = xyz  (pad not written)
// LDS F1/F2/Bs use the XOR 16B-block swizzle (slot = blk ^ (row&7)).
// ---------------------------------------------------------------------------
__global__ __launch_bounds__(512) void sa1_fused(
    const float* __restrict__ xyz, const float* __restrict__ pts,
    const float* __restrict__ w1,
    const float* __restrict__ sc1, const float* __restrict__ sh1,
    const ushort* __restrict__ Wt2,
    const float* __restrict__ sc2, const float* __restrict__ sh2,
    const ushort* __restrict__ Wt3,
    const float* __restrict__ sc3, const float* __restrict__ sh3,
    const float* __restrict__ attw, const float* __restrict__ attb,
    ushort* __restrict__ G) {
    __shared__ ushort F1[128 * 64];    // 16 KB
    __shared__ ushort W2s[128 * 64];   // 16 KB
    __shared__ ushort F2[128 * 128];   // 32 KB
    __shared__ ushort Bs[256 * 64];    // 32 KB
    __shared__ float w1s[384];
    __shared__ float sc1s[64], sh1s[64];
    __shared__ float red[128 * 4];
    __shared__ float sig[128];

    const int tid = threadIdx.x;
    const int bm0 = blockIdx.x * 128;
    const int wid = tid >> 6, ln = tid & 63;
    const int lm = ln & 15, q = ln >> 4;
    const int sx = lm & 7;

    // ---- stage small consts + W2^T (async) ----
    if (tid < 384) w1s[tid] = w1[tid];
    if (tid < 64) { sc1s[tid] = sc1[tid]; sh1s[tid] = sh1[tid]; }
    const int srow = tid >> 3;          // 0..63
    const int sb = tid & 7;
    const int sgb = sb ^ (srow & 7);
#pragma unroll
    for (int l = 0; l < 2; ++l)
        gl_lds16(&Wt2[(size_t)(l * 64 + srow) * 64 + (sgb << 3)],
                 &W2s[l * 4096 + wid * 512]);
    __syncthreads();  // w1s/sc1s visible

    // ---- f1: 1024 chunks of (row, 8 cols); 2 per thread ----
#pragma unroll
    for (int i = 0; i < 2; ++i) {
        int chunk = tid + 512 * i;
        int row = chunk >> 3, blk = chunk & 7;
        int gr = bm0 + row;
        float i0 = xyz[gr * 3], i1 = xyz[gr * 3 + 1], i2 = xyz[gr * 3 + 2];
        float i3 = pts[gr * 3], i4 = pts[gr * 3 + 1], i5 = pts[gr * 3 + 2];
        ushort tmp[8];
#pragma unroll
        for (int j = 0; j < 8; ++j) {
            int c = blk * 8 + j;
            float a = i0 * w1s[c] + i1 * w1s[64 + c] + i2 * w1s[128 + c] +
                      i3 * w1s[192 + c] + i4 * w1s[256 + c] + i5 * w1s[320 + c];
            a = fmaxf(a * sc1s[c] + sh1s[c], 0.0f);
            tmp[j] = f2bf(a);
        }
        int slot = blk ^ (row & 7);
        *(uint4*)&F1[row * 64 + slot * 8] = *(uint4*)tmp;
    }
    asm volatile("s_waitcnt vmcnt(0)" ::: "memory");
    __syncthreads();  // F1 + W2s ready

    // ---- f2 = f1 @ W2 (K=64): wave tile 64(M) x 32(N) ----
    {
        const int wr2 = wid & 1, wc2 = wid >> 1;  // 2 x 4
        floatx4 acc2[4][2];
#pragma unroll
        for (int i = 0; i < 4; ++i)
#pragma unroll
            for (int j = 0; j < 2; ++j) acc2[i][j] = (floatx4){0.f, 0.f, 0.f, 0.f};
#pragma unroll
        for (int h = 0; h < 2; ++h) {
            const int slot = ((h << 2) | q) ^ sx;
            bf16x8 af[4], bf[2];
#pragma unroll
            for (int i = 0; i < 4; ++i)
                af[i] = *(const bf16x8*)(&F1[(wr2 * 64 + i * 16 + lm) * 64 + (slot << 3)]);
#pragma unroll
            for (int i = 0; i < 2; ++i)
                bf[i] = *(const bf16x8*)(&W2s[(wc2 * 32 + i * 16 + lm) * 64 + (slot << 3)]);
#pragma unroll
            for (int mi = 0; mi < 4; ++mi)
#pragma unroll
                for (int ni = 0; ni < 2; ++ni)
                    acc2[mi][ni] = __builtin_amdgcn_mfma_f32_16x16x32_bf16(
                        af[mi], bf[ni], acc2[mi][ni], 0, 0, 0);
        }
        // bn2+relu -> F2 (XOR layout), b16 scatter
        float s2[2], t2[2];
#pragma unroll
        for (int ni = 0; ni < 2; ++ni) {
            int c = wc2 * 32 + ni * 16 + lm;
            s2[ni] = sc2[c]; t2[ni] = sh2[c];
        }
#pragma unroll
        for (int mi = 0; mi < 4; ++mi) {
#pragma unroll
            for (int ni = 0; ni < 2; ++ni) {
                int col = wc2 * 32 + ni * 16 + lm;
                int b = col >> 3;
#pragma unroll
                for (int r = 0; r < 4; ++r) {
                    int row = wr2 * 64 + mi * 16 + q * 4 + r;
                    float val = fmaxf(acc2[mi][ni][r] * s2[ni] + t2[ni], 0.0f);
                    F2[row * 128 + ((b ^ (row & 7)) << 3) + (col & 7)] = f2bf(val);
                }
            }
        }
    }
    __syncthreads();  // F2 ready

    // ---- f3 = f2 @ W3 (K=128, 2 iters of 64): wave tile 64(M) x 64(N) ----
    const int wr3 = wid & 1, wc3 = wid >> 1;  // 2 x 4 -> 128 x 256
    floatx4 acc3[4][4];
#pragma unroll
    for (int i = 0; i < 4; ++i)
#pragma unroll
        for (int j = 0; j < 4; ++j) acc3[i][j] = (floatx4){0.f, 0.f, 0.f, 0.f};

    for (int kt = 0; kt < 128; kt += 64) {
#pragma unroll
        for (int l = 0; l < 4; ++l)
            gl_lds16(&Wt3[(size_t)(l * 64 + srow) * 128 + kt + (sgb << 3)],
                     &Bs[l * 4096 + wid * 512]);
        asm volatile("s_waitcnt vmcnt(0)" ::: "memory");
        __syncthreads();
#pragma unroll
        for (int h = 0; h < 2; ++h) {
            const int slotB = ((h << 2) | q) ^ sx;
            const int gbA = (kt >> 3) + (h << 2) + q;
            const int slotA = gbA ^ sx;
            bf16x8 af[4], bf[4];
#pragma unroll
            for (int i = 0; i < 4; ++i)
                af[i] = *(const bf16x8*)(&F2[(wr3 * 64 + i * 16 + lm) * 128 + (slotA << 3)]);
#pragma unroll
            for (int i = 0; i < 4; ++i)
                bf[i] = *(const bf16x8*)(&Bs[(wc3 * 64 + i * 16 + lm) * 64 + (slotB << 3)]);
#pragma unroll
            for (int mi = 0; mi < 4; ++mi)
#pragma unroll
                for (int ni = 0; ni < 4; ++ni)
                    acc3[mi][ni] = __builtin_amdgcn_mfma_f32_16x16x32_bf16(
                        af[mi], bf[ni], acc3[mi][ni], 0, 0, 0);
        }
        __syncthreads();
    }

    // ---- gate: per-row dot(f3, att1w) across 256 cols ----
    float s3[4], t3[4], aw[4];
#pragma unroll
    for (int ni = 0; ni < 4; ++ni) {
        int c = wc3 * 64 + ni * 16 + lm;
        s3[ni] = sc3[c]; t3[ni] = sh3[c]; aw[ni] = attw[c];
    }
#pragma unroll
    for (int mi = 0; mi < 4; ++mi) {
#pragma unroll
        for (int r = 0; r < 4; ++r) {
            int lrow = wr3 * 64 + mi * 16 + q * 4 + r;
            float p = 0.0f;
#pragma unroll
            for (int ni = 0; ni < 4; ++ni)
                p += fmaxf(acc3[mi][ni][r] * s3[ni] + t3[ni], 0.0f) * aw[ni];
#pragma unroll
            for (int o = 8; o > 0; o >>= 1) p += __shfl_xor(p, o, 16);
            if (lm == 0) red[lrow * 4 + wc3] = p;
        }
    }
    __syncthreads();
    if (tid < 128) {
        float sm = red[tid * 4] + red[tid * 4 + 1] + red[tid * 4 + 2] + red[tid * 4 + 3];
        sig[tid] = 1.0f / (1.0f + expf(-(sm + attb[0])));
    }
    __syncthreads();

    // ---- write G: scaled f3 (cols 0..255) + xyz (256..258); pad skipped ----
#pragma unroll
    for (int mi = 0; mi < 4; ++mi) {
#pragma unroll
        for (int r = 0; r < 4; ++r) {
            int lrow = wr3 * 64 + mi * 16 + q * 4 + r;
            float sg = sig[lrow];
            size_t gb = (size_t)(bm0 + lrow) * 320;
#pragma unroll
            for (int ni = 0; ni < 4; ++ni) {
                int c = wc3 * 64 + ni * 16 + lm;
                float val = fmaxf(acc3[mi][ni][r] * s3[ni] + t3[ni], 0.0f);
                G[gb + c] = f2bf(val * sg);
            }
        }
    }
    if (tid < 128) {
        int gr = bm0 + tid;
        size_t gb = (size_t)gr * 320;
        G[gb + 256] = f2bf(xyz[gr * 3]);
        G[gb + 257] = f2bf(xyz[gr * 3 + 1]);
        G[gb + 258] = f2bf(xyz[gr * 3 + 2]);
    }
}

// ---------------------------------------------------------------------------
// GEMM (R5 config, unchanged): C[M,N] = ReLU(BN(A @ W)), 128x128 tile, BK=64,
// XOR bank-deswizzle, XCD-swizzled grid, ldc param, fused logits for S3.
// ---------------------------------------------------------------------------
__global__ __launch_bounds__(256) void gemm_bn_relu(
    const ushort* __restrict__ A, const ushort* __restrict__ Wt,
    const float* __restrict__ scale, const float* __restrict__ shift,
    ushort* __restrict__ C, int N, int K, int numN, int ldc,
    const float* __restrict__ attw, float* __restrict__ logitsP) {
    __shared__ ushort As[128 * 64];
    __shared__ ushort Bs[128 * 64];
    const int tid = threadIdx.x;
    const int g8 = numN * 8;
    const int chunk = blockIdx.x / g8;
    const int rem = blockIdx.x - chunk * g8;
    const int nt = rem >> 3;
    const int xcd = rem & 7;
    const int bn0 = nt * 128;
    const int bm0 = (chunk * 8 + xcd) * 128;

    const int wid = tid >> 6, ln = tid & 63;
    const int wr = wid >> 1, wc = wid & 1;
    const int lm = ln & 15, q = ln >> 4;
    const int sx = lm & 7;

    floatx4 acc[4][4];
#pragma unroll
    for (int i = 0; i < 4; ++i)
#pragma unroll
        for (int j = 0; j < 4; ++j) acc[i][j] = (floatx4){0.f, 0.f, 0.f, 0.f};

    const int srow = tid >> 3;
    const int sb = tid & 7;
    const int sgb = sb ^ (srow & 7);
    const ushort* aP[4];
    const ushort* bP[4];
#pragma unroll
    for (int l = 0; l < 4; ++l) {
        int row = l * 32 + srow;
        aP[l] = &A[(size_t)(bm0 + row) * K + (sgb << 3)];
        bP[l] = &Wt[(size_t)(bn0 + row) * K + (sgb << 3)];
    }
    ushort* aL = &As[wid * 512];
    ushort* bL = &Bs[wid * 512];

    for (int kt = 0; kt < K; kt += 64) {
#pragma unroll
        for (int l = 0; l < 4; ++l) gl_lds16(aP[l], aL + l * 2048);
#pragma unroll
        for (int l = 0; l < 4; ++l) gl_lds16(bP[l], bL + l * 2048);
#pragma unroll
        for (int l = 0; l < 4; ++l) { aP[l] += 64; bP[l] += 64; }
        asm volatile("s_waitcnt vmcnt(0)" ::: "memory");
        __syncthreads();
#pragma unroll
        for (int h = 0; h < 2; ++h) {
            const int slot = ((h << 2) | q) ^ sx;
            bf16x8 af[4], bf[4];
#pragma unroll
            for (int i = 0; i < 4; ++i)
                af[i] = *(const bf16x8*)(&As[(wr * 64 + i * 16 + lm) * 64 + (slot << 3)]);
#pragma unroll
            for (int i = 0; i < 4; ++i)
                bf[i] = *(const bf16x8*)(&Bs[(wc * 64 + i * 16 + lm) * 64 + (slot << 3)]);
#pragma unroll
            for (int mi = 0; mi < 4; ++mi)
#pragma unroll
                for (int ni = 0; ni < 4; ++ni)
                    acc[mi][ni] = __builtin_amdgcn_mfma_f32_16x16x32_bf16(
                        af[mi], bf[ni], acc[mi][ni], 0, 0, 0);
        }
        __syncthreads();
    }

    float s[4], t[4], aw[4];
#pragma unroll
    for (int ni = 0; ni < 4; ++ni) {
        int gcol = bn0 + wc * 64 + ni * 16 + lm;
        s[ni] = scale[gcol];
        t[ni] = shift[gcol];
        aw[ni] = attw ? attw[gcol] : 0.0f;
    }
#pragma unroll
    for (int mi = 0; mi < 4; ++mi) {
        int grow0 = bm0 + wr * 64 + mi * 16 + q * 4;
#pragma unroll
        for (int r = 0; r < 4; ++r) {
            float p = 0.0f;
#pragma unroll
            for (int ni = 0; ni < 4; ++ni) {
                int gcol = bn0 + wc * 64 + ni * 16 + lm;
                float val = fmaxf(acc[mi][ni][r] * s[ni] + t[ni], 0.0f);
                C[(size_t)(grow0 + r) * ldc + gcol] = f2bf(val);
                p += val * aw[ni];
            }
            if (logitsP) {
#pragma unroll
                for (int o = 8; o > 0; o >>= 1) p += __shfl_xor(p, o, 16);
                if (lm == 0)
                    logitsP[(size_t)(nt * 2 + wc) * M_ROWS + grow0 + r] = p;
            }
        }
    }
}

// ---------------------------------------------------------------------------
// Softmax over N=4096 per batch (logits = sum of 16 partial slices).
// ---------------------------------------------------------------------------
__global__ __launch_bounds__(1024) void softmax_kernel(
    const float* __restrict__ logitsP, float* __restrict__ alpha) {
    __shared__ float red[1024];
    int b = blockIdx.x, t = threadIdx.x;
    float4 v = (float4){0.f, 0.f, 0.f, 0.f};
#pragma unroll
    for (int j = 0; j < 16; ++j) {
        float4 pv = *(const float4*)&logitsP[(size_t)j * M_ROWS + b * 4096 + t * 4];
        v.x += pv.x; v.y += pv.y; v.z += pv.z; v.w += pv.w;
    }
    float mx = fmaxf(fmaxf(v.x, v.y), fmaxf(v.z, v.w));
    red[t] = mx;
    __syncthreads();
    for (int s = 512; s > 0; s >>= 1) {
        if (t < s) red[t] = fmaxf(red[t], red[t + s]);
        __syncthreads();
    }
    float M = red[0];
    __syncthreads();
    float e0 = expf(v.x - M), e1 = expf(v.y - M), e2 = expf(v.z - M), e3 = expf(v.w - M);
    red[t] = e0 + e1 + e2 + e3;
    __syncthreads();
    for (int s = 512; s > 0; s >>= 1) {
        if (t < s) red[t] += red[t + s];
        __syncthreads();
    }
    float inv = 1.0f / red[0];
    *(float4*)&alpha[b * 4096 + t * 4] = make_float4(e0 * inv, e1 * inv, e2 * inv, e3 * inv);
}

// ---------------------------------------------------------------------------
// Pool: pooled[b,c] = sum_n alpha[b,n]*g3[b,n,c]; thread: 4 cols (ushort4)
// ---------------------------------------------------------------------------
__global__ __launch_bounds__(256) void pool_kernel(
    const ushort* __restrict__ g3, const float* __restrict__ alpha,
    float* __restrict__ pooled) {
    int c4 = threadIdx.x * 4;
    int b = blockIdx.y;
    int n0 = blockIdx.z * 128;
    const ushort* base = g3 + ((size_t)b * 4096 + n0) * 1024 + c4;
    const float* al = alpha + b * 4096 + n0;
    float a0 = 0.f, a1 = 0.f, a2 = 0.f, a3 = 0.f;
#pragma unroll 4
    for (int n = 0; n < 128; ++n) {
        float w = al[n];
        ushort4 gv = *(const ushort4*)&base[(size_t)n * 1024];
        a0 += w * b2f(gv.x); a1 += w * b2f(gv.y);
        a2 += w * b2f(gv.z); a3 += w * b2f(gv.w);
    }
    float* pd = &pooled[b * 1024 + c4];
    atomicAdd(pd + 0, a0); atomicAdd(pd + 1, a1);
    atomicAdd(pd + 2, a2); atomicAdd(pd + 3, a3);
}

// ---------------------------------------------------------------------------
// Heads: wave-per-output, transposed fp32 weights (contiguous float4 reads)
// ---------------------------------------------------------------------------
__global__ __launch_bounds__(256) void head1_kernel(
    const float* __restrict__ pooled, const float* __restrict__ wt1,
    const float* __restrict__ g, const float* __restrict__ bb,
    const float* __restrict__ m, const float* __restrict__ v,
    float* __restrict__ h1) {
    int wv = (blockIdx.x * 256 + threadIdx.x) >> 6;
    int ln = threadIdx.x & 63;
    int b = wv >> 9, c = wv & 511;
    const float4* wp = (const float4*)&wt1[(size_t)c * 1024];
    const float4* pp = (const float4*)&pooled[b * 1024];
    float s = 0.f;
#pragma unroll
    for (int j = 0; j < 4; ++j) {
        float4 w4 = wp[ln * 4 + j], p4 = pp[ln * 4 + j];
        s += w4.x * p4.x + w4.y * p4.y + w4.z * p4.z + w4.w * p4.w;
    }
#pragma unroll
    for (int o = 32; o > 0; o >>= 1) s += __shfl_xor(s, o);
    if (ln == 0) {
        float sc = g[c] * rsqrtf(v[c] + 1e-5f);
        float sh = bb[c] - m[c] * sc;
        h1[b * 512 + c] = fmaxf(s * sc + sh, 0.0f);
    }
}

__global__ __launch_bounds__(256) void head2_kernel(
    const float* __restrict__ h1, const float* __restrict__ wt2,
    const float* __restrict__ g, const float* __restrict__ bb,
    const float* __restrict__ m, const float* __restrict__ v,
    float* __restrict__ h2) {
    int wv = (blockIdx.x * 256 + threadIdx.x) >> 6;
    int ln = threadIdx.x & 63;
    int b = wv >> 8, c = wv & 255;
    const float4* wp = (const float4*)&wt2[(size_t)c * 512];
    const float4* pp = (const float4*)&h1[b * 512];
    float s = 0.f;
#pragma unroll
    for (int j = 0; j < 2; ++j) {
        float4 w4 = wp[ln * 2 + j], p4 = pp[ln * 2 + j];
        s += w4.x * p4.x + w4.y * p4.y + w4.z * p4.z + w4.w * p4.w;
    }
#pragma unroll
    for (int o = 32; o > 0; o >>= 1) s += __shfl_xor(s, o);
    if (ln == 0) {
        float sc = g[c] * rsqrtf(v[c] + 1e-5f);
        float sh = bb[c] - m[c] * sc;
        h2[b * 256 + c] = fmaxf(s * sc + sh, 0.0f);
    }
}

__global__ __launch_bounds__(64) void head3_kernel(
    const float* __restrict__ h2, const float* __restrict__ pw,
    const float* __restrict__ pb, float* __restrict__ out) {
    int b = blockIdx.x, ln = threadIdx.x;
    float4 hv = *(const float4*)&h2[b * 256 + ln * 4];
    float4 wv = *(const float4*)&pw[ln * 4];
    float sum = hv.x * wv.x + hv.y * wv.y + hv.z * wv.z + hv.w * wv.w;
#pragma unroll
    for (int o = 32; o > 0; o >>= 1) sum += __shfl_xor(sum, o);
    if (ln == 0) out[b] = sum + pb[0];
}

// ---------------------------------------------------------------------------
extern "C" void kernel_launch(void* const* d_in, const int* in_sizes, int n_in,
                              void* d_out, int out_size, void* d_ws, size_t ws_size,
                              hipStream_t stream) {
    (void)in_sizes; (void)n_in; (void)out_size; (void)ws_size;
    const float* xyz = (const float*)d_in[0];
    const float* pts = (const float*)d_in[1];
    const float* sa1_w1 = (const float*)d_in[2];
    const float* bn1g = (const float*)d_in[3];
    const float* bn1b = (const float*)d_in[4];
    const float* bn1m = (const float*)d_in[5];
    const float* bn1v = (const float*)d_in[6];
    const float* sa1_w2 = (const float*)d_in[7];
    const float* bn2g = (const float*)d_in[8];
    const float* bn2b = (const float*)d_in[9];
    const float* bn2m = (const float*)d_in[10];
    const float* bn2v = (const float*)d_in[11];
    const float* sa1_w3 = (const float*)d_in[12];
    const float* bn3g = (const float*)d_in[13];
    const float* bn3b = (const float*)d_in[14];
    const float* bn3m = (const float*)d_in[15];
    const float* bn3v = (const float*)d_in[16];
    const float* att1w = (const float*)d_in[17];
    const float* att1b = (const float*)d_in[18];
    const float* sa3_w1 = (const float*)d_in[19];
    const float* s1g = (const float*)d_in[20];
    const float* s1b = (const float*)d_in[21];
    const float* s1m = (const float*)d_in[22];
    const float* s1v = (const float*)d_in[23];
    const float* sa3_w2 = (const float*)d_in[24];
    const float* s2g = (const float*)d_in[25];
    const float* s2b = (const float*)d_in[26];
    const float* s2m = (const float*)d_in[27];
    const float* s2v = (const float*)d_in[28];
    const float* sa3_w3 = (const float*)d_in[29];
    const float* s3g = (const float*)d_in[30];
    const float* s3b = (const float*)d_in[31];
    const float* s3m = (const float*)d_in[32];
    const float* s3v = (const float*)d_in[33];
    const float* att3w = (const float*)d_in[34];
    const float* fc1w = (const float*)d_in[35];
    const float* h1g = (const float*)d_in[36];
    const float* h1b = (const float*)d_in[37];
    const float* h1m = (const float*)d_in[38];
    const float* h1v = (const float*)d_in[39];
    const float* fc2w = (const float*)d_in[40];
    const float* h2g = (const float*)d_in[41];
    const float* h2b = (const float*)d_in[42];
    const float* h2m = (const float*)d_in[43];
    const float* h2v = (const float*)d_in[44];
    const float* predw = (const float*)d_in[45];
    const float* predb = (const float*)d_in[46];
    float* out = (float*)d_out;

    // ---- workspace ----
    char* wsb = (char*)d_ws;
    size_t off = 0;
    auto alloc = [&](size_t bytes) -> void* {
        off = (off + 255) & ~(size_t)255;
        void* p = wsb + off;
        off += bytes;
        return p;
    };
    ushort* Wt2 = (ushort*)alloc(128 * 64 * 2);
    ushort* Wt3 = (ushort*)alloc(256 * 128 * 2);
    ushort* WtS1 = (ushort*)alloc(256 * 320 * 2);
    ushort* WtS2 = (ushort*)alloc(512 * 256 * 2);
    ushort* WtS3 = (ushort*)alloc(1024 * 512 * 2);
    float* wt1 = (float*)alloc(512 * 1024 * 4);
    float* wt2 = (float*)alloc(256 * 512 * 4);
    float* sc1 = (float*)alloc(64 * 4);   float* sh1 = (float*)alloc(64 * 4);
    float* sc2 = (float*)alloc(128 * 4);  float* sh2 = (float*)alloc(128 * 4);
    float* sc3 = (float*)alloc(256 * 4);  float* sh3 = (float*)alloc(256 * 4);
    float* scS1 = (float*)alloc(256 * 4); float* shS1 = (float*)alloc(256 * 4);
    float* scS2 = (float*)alloc(512 * 4); float* shS2 = (float*)alloc(512 * 4);
    float* scS3 = (float*)alloc(1024 * 4); float* shS3 = (float*)alloc(1024 * 4);
    float* logitsP = (float*)alloc((size_t)16 * M_ROWS * 4);
    float* alpha = (float*)alloc((size_t)M_ROWS * 4);
    float* pooled = (float*)alloc(16 * 1024 * 4);
    float* h1buf = (float*)alloc(16 * 512 * 4);
    float* h2buf = (float*)alloc(16 * 256 * 4);

    // big region, overlaid by live range.
    off = (off + MB - 1) & ~(MB - 1);
    char* bigA = wsb + off;            // 128 MB
    char* bigB = bigA + 128 * MB;      // 64 MB
    ushort* G  = (ushort*)(bigA);             // 40 MB  [fused, S1)
    ushort* g1 = (ushort*)(bigA + 40 * MB);   // 32 MB  [S1, S2)
    ushort* g3 = (ushort*)(bigA);             // 128 MB [S3, pool)
    ushort* g2 = (ushort*)(bigB);             // 64 MB  [S2, S3)

    // ---- prep2 ----
    Prep2Args pa;
    const float* srcs[7] = {sa1_w2, sa1_w3, sa3_w1, sa3_w2, sa3_w3, fc1w, fc2w};
    void* dsts[7] = {Wt2, Wt3, WtS1, WtS2, WtS3, wt1, wt2};
    int Ks[7] = {64, 128, 320, 256, 512, 1024, 512};
    int Ns[7] = {128, 256, 256, 512, 1024, 512, 256};
    int Kps[7] = {64, 128, 320, 256, 512, 1024, 512};
    int isBF[7] = {1, 1, 1, 1, 1, 0, 0};
    int maxTiles = 0;
    for (int i = 0; i < 7; ++i) {
        pa.src[i] = srcs[i]; pa.dst[i] = dsts[i];
        pa.K[i] = Ks[i]; pa.N[i] = Ns[i]; pa.Kp[i] = Kps[i];
        pa.isBF[i] = isBF[i];
        pa.tiles[i] = (Kps[i] >> 5) * (Ns[i] >> 5);
        if (pa.tiles[i] > maxTiles) maxTiles = pa.tiles[i];
    }
    const float* gs[6] = {bn1g, bn2g, bn3g, s1g, s2g, s3g};
    const float* bbs[6] = {bn1b, bn2b, bn3b, s1b, s2b, s3b};
    const float* mms[6] = {bn1m, bn2m, bn3m, s1m, s2m, s3m};
    const float* vvs[6] = {bn1v, bn2v, bn3v, s1v, s2v, s3v};
    float* scs[6] = {sc1, sc2, sc3, scS1, scS2, scS3};
    float* shs[6] = {sh1, sh2, sh3, shS1, shS2, shS3};
    int Cs[6] = {64, 128, 256, 256, 512, 1024};
    for (int i = 0; i < 6; ++i) {
        pa.g[i] = gs[i]; pa.bb[i] = bbs[i]; pa.mm[i] = mms[i]; pa.vv[i] = vvs[i];
        pa.sc[i] = scs[i]; pa.sh[i] = shs[i]; pa.C[i] = Cs[i];
    }
    pa.pooled = pooled;
    prep2_kernel<<<dim3(maxTiles, 8), 256, 0, stream>>>(pa);

    // ---- SA1 fused front: xyz/pts -> G ----
    sa1_fused<<<M_ROWS / 128, 512, 0, stream>>>(
        xyz, pts, sa1_w1, sc1, sh1, Wt2, sc2, sh2, Wt3, sc3, sh3,
        att1w, att1b, G);
    // ---- SA3 ----
    gemm_bn_relu<<<512 * 2, 256, 0, stream>>>(G, WtS1, scS1, shS1, g1, 256, 320, 2, 256, nullptr, nullptr);
    gemm_bn_relu<<<512 * 4, 256, 0, stream>>>(g1, WtS2, scS2, shS2, g2, 512, 256, 4, 512, nullptr, nullptr);
    gemm_bn_relu<<<512 * 8, 256, 0, stream>>>(g2, WtS3, scS3, shS3, g3, 1024, 512, 8, 1024, att3w, logitsP);
    // ---- attention pooling ----
    softmax_kernel<<<16, 1024, 0, stream>>>(logitsP, alpha);
    pool_kernel<<<dim3(1, 16, 32), 256, 0, stream>>>(g3, alpha, pooled);
    // ---- head ----
    head1_kernel<<<2048, 256, 0, stream>>>(pooled, wt1, h1g, h1b, h1m, h1v, h1buf);
    head2_kernel<<<1024, 256, 0, stream>>>(h1buf, wt2, h2g, h2b, h2m, h2v, h2buf);
    head3_kernel<<<16, 64, 0, stream>>>(h2buf, predw, predb, out);
}